// Round 7
// baseline (344.744 us; speedup 1.0000x reference)
//
#include <hip/hip_runtime.h>
#include <math.h>

#define NL     24
#define HIDDEN 512
#define H3     1536
#define HD     32
#define CAPCTX 2048
#define FFD    2048
#define NVOCAB 1025
#define GRID   256
#define NT     256
#define EPSLN  1e-5f
#define ISQ    0.17677669529663687f  /* 1/sqrt(32) */

// ---- agent-scope (LLC-coherent, relaxed) helpers ---------------------------
__device__ __forceinline__ float gld(const float* p){ return __hip_atomic_load(p, __ATOMIC_RELAXED, __HIP_MEMORY_SCOPE_AGENT); }
__device__ __forceinline__ void  gst(float* p, float v){ __hip_atomic_store(p, v, __ATOMIC_RELAXED, __HIP_MEMORY_SCOPE_AGENT); }
__device__ __forceinline__ int   ild(const int* p){ return __hip_atomic_load(p, __ATOMIC_RELAXED, __HIP_MEMORY_SCOPE_AGENT); }

__device__ __forceinline__ void done_add(int* ctr, int tid){
  __syncthreads();   // drains vmcnt(0): all block stores/atomics at LLC first
  if (tid == 0) __hip_atomic_fetch_add(ctr, 1, __ATOMIC_RELAXED, __HIP_MEMORY_SCOPE_AGENT);
}
__device__ __forceinline__ void waitge1(const int* c, int tgt){
  if (threadIdx.x == 0){
    int g = 0;
    while (__hip_atomic_load(c, __ATOMIC_RELAXED, __HIP_MEMORY_SCOPE_AGENT) < tgt){
      if (++g > (1<<25)) break;   // safety: never hang the harness
    }
  }
  __syncthreads();
}
__device__ __forceinline__ void waitgeN(const int* base, int n, int tgt){
  if ((int)threadIdx.x < n){
    const int* c = base + threadIdx.x*16;
    int g = 0;
    while (__hip_atomic_load(c, __ATOMIC_RELAXED, __HIP_MEMORY_SCOPE_AGENT) < tgt){
      if (++g > (1<<25)) break;
    }
  }
  __syncthreads();
}
#define PIN() asm volatile("" ::: "memory")

// counter map (each on its own 64B line, int units)
#define HEADC(h)  ((h)*16)           // 16 head counters (nch adds/layer)
#define FF1G(g)   ((16+(g))*16)      // 8 ffn groups (16 adds/layer)
#define PRED_C    (24*16)            // 65 adds
#define SLINE(par,h) ((26 + (par)*16 + (h))*16)  // fp32 S accumulators

struct LdsF { float xn[HIDDEN]; float red[16*17]; float r8[8]; float s16[16]; float h16[16]; };
struct LdsAt{ float xn[HIDDEN]; float q[HD]; float kv[64]; float e[128]; float v[128*33]; float red[792]; float r8[8]; float o32[HD]; };
union  Lds  { LdsF f; LdsAt a; };

__device__ __forceinline__ void bsum2(float &a, float &bb, float* lds8, int tid){
  #pragma unroll
  for (int o=32;o;o>>=1){ a += __shfl_down(a,o); bb += __shfl_down(bb,o); }
  __syncthreads();
  if ((tid&63)==0){ int w=tid>>6; lds8[w]=a; lds8[4+w]=bb; }
  __syncthreads();
  a  = lds8[0]+lds8[1]+lds8[2]+lds8[3];
  bb = lds8[4]+lds8[5]+lds8[6]+lds8[7];
  __syncthreads();
}

// KV copy + tail-zero share: sharer idx in [0,T), rows p != clen
__device__ __forceinline__ void kvcopy(int idx, int T, int l, int clen,
    const float* __restrict__ KC, const float* __restrict__ VC,
    float* KO, float* VO, int tid){
  const int t7 = tid & 127, halfr = tid >> 7;
  const float4 z4 = make_float4(0.f,0.f,0.f,0.f);
  for (int r0 = idx*2; r0 < 4096; r0 += 2*T){
    int r = r0 + halfr;
    int p = r & 2047, isv = r >> 11;
    if (p != clen){
      float4* dst = (float4*)((isv ? VO : KO) + ((size_t)l*CAPCTX + p)*HIDDEN);
      if (p < clen){
        const float4* src = (const float4*)((isv ? VC : KC) + ((size_t)l*CAPCTX + p)*HIDDEN);
        dst[t7] = src[t7];
      } else {
        dst[t7] = z4;
      }
    }
  }
}

__global__ __launch_bounds__(NT, 1)
void t2s_decode(const int* __restrict__ LT, const int* __restrict__ PI, const int* __restrict__ CL,
                const float* __restrict__ KC, const float* __restrict__ VC,
                const float* __restrict__ EMB, const float* __restrict__ PE,
                const float* __restrict__ XSc, const float* __restrict__ ALp,
                const float* __restrict__ QKVW, const float* __restrict__ QKVB,
                const float* __restrict__ OUTW, const float* __restrict__ OUTB,
                const float* __restrict__ NW1, const float* __restrict__ NB1,
                const float* __restrict__ NW2, const float* __restrict__ NB2,
                const float* __restrict__ W1, const float* __restrict__ B1,
                const float* __restrict__ W2, const float* __restrict__ B2,
                const float* __restrict__ PW, const float* __restrict__ PB,
                float* __restrict__ OUT, float* __restrict__ WS)
{
  __shared__ Lds L;
  const int b = blockIdx.x, tid = threadIdx.x;

  int* C = (int*)WS;                 // 64 lines x 64B (zeroed by memset)
  float* F   = WS + 1024;            // floats from byte 4096
  float* wop = F;                    // [2][16][512] unnormalized out-proj sums
  float* wf2 = F + 16384;            // [2][8][512]  ff2 partial sums
  float* wx  = F + 24576;            // [512] layer input x (attn input)
  float* wx1 = F + 25088;            // [512] LN1 output

  float* KO = OUT + 1029;
  float* VO = KO + (size_t)NL*CAPCTX*HIDDEN;

  const int token = LT[0], posi = PI[0], clen = CL[0], nlen = clen + 1;
  const int nch = (nlen + 127) >> 7;       // <= 8 for this problem
  const int T_copy = 128 + 16*(8 - nch);   // kv-copy sharers

  // ======================= ATTENTION BLOCKS (128..255) ======================
  if (b >= 128){
    const int t = b - 128, h = t & 15, ci = t >> 4;
    const int cstar = clen >> 7;             // == nch-1

    if (ci >= nch){
      // idle chunk slot: pure copy duty, no sync
      const int idx = 128 + (ci - nch)*16 + h;
      for (int l=0;l<NL;l++) kvcopy(idx, T_copy, l, clen, KC, VC, KO, VO, tid);
    } else {
      const int c = tid & 31, s5 = tid >> 5;          // gemv mapping
      const int pl = tid >> 1, half = tid & 1, dbase = half << 4;
      const int p = (ci << 7) + pl;
      const bool validp = (p < nlen);
      const bool isnew  = validp && (p == clen);
      const bool iscstar = (ci == cstar);

      for (int l=0;l<NL;l++){
        const int par = l & 1;
        // ---- prefetch (issued before the gate; drains during the spin) -----
        float pfQ[64], pfK[64], pfV[64];
        float qb, kb = 0.f, vb = 0.f;
        {
          const float* Wq = QKVW + (size_t)l*HIDDEN*H3 + (size_t)s5*H3 + h*HD + c;
          #pragma unroll
          for (int k=0;k<64;k++) pfQ[k] = Wq[(size_t)(k*8)*H3];
          qb = QKVB[(size_t)l*H3 + h*HD + c];
          if (iscstar){
            const float* Wk = QKVW + (size_t)l*HIDDEN*H3 + (size_t)s5*H3 + HIDDEN + h*HD + c;
            const float* Wv = Wk + HIDDEN;
            #pragma unroll
            for (int k=0;k<64;k++){ pfK[k] = Wk[(size_t)(k*8)*H3]; pfV[k] = Wv[(size_t)(k*8)*H3]; }
            kb = QKVB[(size_t)l*H3 + HIDDEN + h*HD + c];
            vb = QKVB[(size_t)l*H3 + 2*HIDDEN + h*HD + c];
          }
        }
        float pfO[64];
        {
          const float* Wo = OUTW + (size_t)l*HIDDEN*HIDDEN + (size_t)(h*HD)*HIDDEN + tid;
          #pragma unroll
          for (int d=0;d<32;d++){ pfO[d] = Wo[(size_t)d*HIDDEN]; pfO[32+d] = Wo[(size_t)d*HIDDEN + 256]; }
        }
        float kbuf[16], vbuf[16];
        if (validp && !isnew){
          const size_t rowoff = ((size_t)l*CAPCTX + p)*HIDDEN + h*HD + dbase;
          const float4* sk = (const float4*)(KC + rowoff);
          const float4* sv = (const float4*)(VC + rowoff);
          #pragma unroll
          for (int k4=0;k4<4;k4++){
            float4 a = sk[k4];
            kbuf[4*k4]=a.x; kbuf[4*k4+1]=a.y; kbuf[4*k4+2]=a.z; kbuf[4*k4+3]=a.w;
            float4 cc = sv[k4];
            vbuf[4*k4]=cc.x; vbuf[4*k4+1]=cc.y; vbuf[4*k4+2]=cc.z; vbuf[4*k4+3]=cc.w;
          }
        }
        float lnb[2]={0,0}, lnw[2]={0,0}, lnn[2]={0,0};
        if (l > 0){
          #pragma unroll
          for (int r=0;r<2;r++){
            int i = tid + r*NT;
            lnb[r] = B2[(size_t)(l-1)*HIDDEN + i];
            lnw[r] = NW2[(size_t)(l-1)*HIDDEN + i];
            lnn[r] = NB2[(size_t)(l-1)*HIDDEN + i];
          }
        }
        PIN();

        // ---- gate on previous layer's ffn ---------------------------------
        if (l > 0) waitgeN(C + FF1G(0), 8, 16*l);

        // ---- build xn (layer input) redundantly ---------------------------
        float xn0, xn1;
        if (l == 0){
          float xs = XSc[0], al = ALp[0];
          xn0 = EMB[(size_t)token*HIDDEN + tid]*xs       + al*PE[(size_t)posi*HIDDEN + tid];
          xn1 = EMB[(size_t)token*HIDDEN + tid + 256]*xs + al*PE[(size_t)posi*HIDDEN + tid + 256];
        } else {
          float t0 = gld(&wx1[tid]) + lnb[0];
          float t1 = gld(&wx1[tid+256]) + lnb[1];
          const float* f2p = wf2 + (par^1)*4096;
          #pragma unroll
          for (int rg=0; rg<8; rg++){
            t0 += gld(&f2p[rg*512 + tid]);
            t1 += gld(&f2p[rg*512 + tid + 256]);
          }
          float s1 = t0 + t1, s2 = t0*t0 + t1*t1;
          bsum2(s1, s2, L.a.r8, tid);
          float mu = s1*(1.f/HIDDEN), rstd = rsqrtf(s2*(1.f/HIDDEN)-mu*mu+EPSLN);
          xn0 = (t0-mu)*rstd*lnw[0] + lnn[0];
          xn1 = (t1-mu)*rstd*lnw[1] + lnn[1];
        }
        L.a.xn[tid] = xn0; L.a.xn[tid+256] = xn1;
        if (b == 128){ gst(&wx[tid], xn0); gst(&wx[tid+256], xn1); }
        __syncthreads();

        // ---- fused q (+k/v on cstar) GEMV ---------------------------------
        {
          float qa = 0.f, ka = 0.f, va = 0.f;
          #pragma unroll
          for (int k=0;k<64;k++){
            float xv = L.a.xn[s5 + 8*k];
            qa += xv * pfQ[k];
            if (iscstar){ ka += xv * pfK[k]; va += xv * pfV[k]; }
          }
          L.a.red[s5*33 + c] = qa;
          if (iscstar){ L.a.red[264 + s5*33 + c] = ka; L.a.red[528 + s5*33 + c] = va; }
          __syncthreads();
          if (tid < 32){
            float qs = 0.f;
            #pragma unroll
            for (int k=0;k<8;k++) qs += L.a.red[k*33 + tid];
            L.a.q[tid] = (qs + qb) * ISQ;
            if (iscstar){
              float ks = 0.f, vs = 0.f;
              #pragma unroll
              for (int k=0;k<8;k++){ ks += L.a.red[264 + k*33 + tid]; vs += L.a.red[528 + k*33 + tid]; }
              ks += kb; vs += vb;
              L.a.kv[tid] = ks; L.a.kv[32+tid] = vs;
              KO[((size_t)l*CAPCTX + clen)*HIDDEN + h*HD + tid] = ks;
              VO[((size_t)l*CAPCTX + clen)*HIDDEN + h*HD + tid] = vs;
            }
          }
          __syncthreads();
        }

        // ---- scores + exp (no max-subtraction; bounded scores) ------------
        float e = 0.f;
        if (validp){
          if (isnew){
            #pragma unroll
            for (int k=0;k<16;k++){ kbuf[k] = L.a.kv[dbase+k]; vbuf[k] = L.a.kv[32+dbase+k]; }
          }
          float dot = 0.f;
          #pragma unroll
          for (int k=0;k<16;k++) dot += kbuf[k] * L.a.q[dbase + k];
          dot += __shfl_xor(dot, 1);
          e = __expf(dot);
        } else {
          #pragma unroll
          for (int k=0;k<16;k++) vbuf[k] = 0.f;
        }
        if (half == 0) L.a.e[pl] = validp ? e : 0.f;
        #pragma unroll
        for (int k=0;k<16;k++) L.a.v[pl*33 + dbase + k] = vbuf[k];
        __syncthreads();

        // ---- combined o-partial + S reduction (one barrier window) --------
        {
          const int d = tid & 31, grp = tid >> 5;
          float oacc = 0.f;
          #pragma unroll
          for (int q2=0;q2<16;q2++){ int pp = (grp<<4) + q2; oacc += L.a.e[pp] * L.a.v[pp*33 + d]; }
          L.a.red[tid] = oacc;
          float se = (tid < 128) ? L.a.e[tid] : 0.f;
          #pragma unroll
          for (int o=32;o;o>>=1) se += __shfl_xor(se, o);
          if ((tid&63)==0) L.a.r8[tid>>6] = se;
          __syncthreads();
          if (tid == 0){
            float S_ci = L.a.r8[0]+L.a.r8[1]+L.a.r8[2]+L.a.r8[3];
            unsafeAtomicAdd((float*)(C + SLINE(par,h)), S_ci);
          }
          if (tid < 32){
            float o8 = 0.f;
            #pragma unroll
            for (int g=0; g<8; g++) o8 += L.a.red[tid + (g<<5)];
            L.a.o32[tid] = o8;
          }
          __syncthreads();
        }

        // ---- fused out-proj: o_ci @ OW_h -> atomic into wop[par][h] -------
        {
          float a0 = 0.f, a1 = 0.f;
          #pragma unroll
          for (int d=0; d<32; d++){ a0 += L.a.o32[d]*pfO[d]; a1 += L.a.o32[d]*pfO[32+d]; }
          unsafeAtomicAdd(&wop[par*8192 + h*512 + tid], a0);
          unsafeAtomicAdd(&wop[par*8192 + h*512 + 256 + tid], a1);
        }
        done_add(&C[HEADC(h)], tid);
      }
    }
    return;
  }

  // ========================= FFN BLOCKS (0..127) ============================
  {
    const int f = b, rgrp = f >> 4;

    for (int l=0;l<NL;l++){
      const int par = l & 1;
      // ---- prefetch -------------------------------------------------------
      float pfF1[32];
      {
        const float* W1p = W1 + (size_t)l*HIDDEN*FFD + (size_t)(tid>>4)*FFD + f*16 + (tid&15);
        #pragma unroll
        for (int k=0;k<32;k++) pfF1[k] = W1p[(size_t)(k*16)*FFD];
      }
      float pfF2[32];
      {
        const float* W2p = W2 + (size_t)l*FFD*HIDDEN + (size_t)(f*16)*HIDDEN + tid;
        #pragma unroll
        for (int cc=0;cc<16;cc++){ pfF2[cc] = W2p[(size_t)cc*HIDDEN]; pfF2[16+cc] = W2p[(size_t)cc*HIDDEN + 256]; }
      }
      float pfOB[2], pfW1n[2], pfB1n[2];
      #pragma unroll
      for (int r=0;r<2;r++){
        int i = tid + r*NT;
        pfOB[r]  = OUTB[(size_t)l*HIDDEN + i];
        pfW1n[r] = NW1[(size_t)l*HIDDEN + i];
        pfB1n[r] = NB1[(size_t)l*HIDDEN + i];
      }
      float pfB1f = B1[(size_t)l*FFD + f*16 + (tid&15)];
      PIN();

      // ---- copy duty (hidden under attention) -----------------------------
      kvcopy(f, T_copy, l, clen, KC, VC, KO, VO, tid);

      // ---- gate on attention ----------------------------------------------
      waitgeN(C + HEADC(0), 16, nch*(l+1));

      // ---- zero next-parity accumulators (safe: HEADC(l) => FF1G(l-1) full)
      if (tid < 64) gst(&wop[(par^1)*8192 + (f>>3)*512 + (f&7)*64 + tid], 0.f);
      if (tid < 32) gst(&wf2[(par^1)*4096 + f*32 + tid], 0.f);
      if (f < 16 && tid == 0) gst((float*)(C + SLINE(par^1, f)), 0.f);

      // ---- LN1 build: t = wx + OUTB + sum_h wop[h]/S_h --------------------
      if (tid < 16) L.f.s16[tid] = 1.f / gld((const float*)(C + SLINE(par, tid)));
      __syncthreads();
      float t0 = gld(&wx[tid]) + pfOB[0];
      float t1 = gld(&wx[tid+256]) + pfOB[1];
      #pragma unroll
      for (int h2=0; h2<16; h2++){
        float is = L.f.s16[h2];
        t0 += gld(&wop[par*8192 + h2*512 + tid]) * is;
        t1 += gld(&wop[par*8192 + h2*512 + tid + 256]) * is;
      }
      float s1 = t0 + t1, s2 = t0*t0 + t1*t1;
      bsum2(s1, s2, L.f.r8, tid);
      float mu = s1*(1.f/HIDDEN), rstd = rsqrtf(s2*(1.f/HIDDEN)-mu*mu+EPSLN);
      float xn0 = (t0-mu)*rstd*pfW1n[0] + pfB1n[0];
      float xn1 = (t1-mu)*rstd*pfW1n[1] + pfB1n[1];
      L.f.xn[tid] = xn0; L.f.xn[tid+256] = xn1;
      if (f == 0){ gst(&wx1[tid], xn0); gst(&wx1[tid+256], xn1); }
      __syncthreads();

      // ---- ff1 (16 cols, inlined reduce) + fused ff2 tile -----------------
      {
        const int cc = tid & 15, s = tid >> 4;
        float a = 0.f;
        #pragma unroll
        for (int k=0;k<32;k++) a += L.f.xn[s + 16*k] * pfF1[k];
        L.f.red[s*17 + cc] = a;
        __syncthreads();
        if (tid < 16){
          float dd = 0.f;
          #pragma unroll
          for (int k=0;k<16;k++) dd += L.f.red[k*17 + tid];
          L.f.h16[tid] = fmaxf(dd + pfB1f, 0.f);
        }
        __syncthreads();
      }
      float a0 = 0.f, a1 = 0.f;
      #pragma unroll
      for (int cc=0; cc<16; cc++){ float hv = L.f.h16[cc]; a0 += hv*pfF2[cc]; a1 += hv*pfF2[16+cc]; }
      unsafeAtomicAdd(&wf2[par*4096 + rgrp*512 + tid], a0);
      unsafeAtomicAdd(&wf2[par*4096 + rgrp*512 + 256 + tid], a1);
      done_add(&C[FF1G(rgrp)], tid);
    }

    // ---- pred logits (ffn blocks 0..64) ------------------------------------
    if (f < 65){
      const int v0 = f << 4;
      const int nrows = (f == 64) ? 1 : 16;
      const int rr = tid >> 4, s2l = tid & 15;
      float pfP[32]; float pfPb = 0.f;
      if (rr < nrows){
        const float* row = PW + (size_t)(v0+rr)*HIDDEN;
        #pragma unroll
        for (int mm=0; mm<32; mm++) pfP[mm] = row[s2l + (mm<<4)];
        pfPb = PB[v0+rr];
      }
      float lnb[2], lnw[2], lnn[2];
      #pragma unroll
      for (int r=0;r<2;r++){
        int i = tid + r*NT;
        lnb[r] = B2[(size_t)(NL-1)*HIDDEN + i];
        lnw[r] = NW2[(size_t)(NL-1)*HIDDEN + i];
        lnn[r] = NB2[(size_t)(NL-1)*HIDDEN + i];
      }
      PIN();
      waitgeN(C + FF1G(0), 8, 16*NL);
      float t0 = gld(&wx1[tid]) + lnb[0];
      float t1 = gld(&wx1[tid+256]) + lnb[1];
      const float* f2p = wf2 + 4096;        // layer-23 parity = 1
      #pragma unroll
      for (int rg=0; rg<8; rg++){
        t0 += gld(&f2p[rg*512 + tid]);
        t1 += gld(&f2p[rg*512 + tid + 256]);
      }
      float s1 = t0 + t1, s2 = t0*t0 + t1*t1;
      bsum2(s1, s2, L.f.r8, tid);
      float mu = s1*(1.f/HIDDEN), rstd = rsqrtf(s2*(1.f/HIDDEN)-mu*mu+EPSLN);
      L.f.xn[tid]     = (t0-mu)*rstd*lnw[0] + lnn[0];
      L.f.xn[tid+256] = (t1-mu)*rstd*lnw[1] + lnn[1];
      __syncthreads();
      if (rr < nrows){
        float acc = 0.f;
        #pragma unroll
        for (int mm=0; mm<32; mm++) acc += L.f.xn[s2l + (mm<<4)] * pfP[mm];
        #pragma unroll
        for (int o=1;o<16;o<<=1) acc += __shfl_xor(acc, o);
        if (s2l == 0) gst(&OUT[v0+rr], acc + pfPb);
      }
      done_add(&C[PRED_C], tid);
    }

    // ---- final: argmax + scalars (block 0) ---------------------------------
    if (b == 0){
      waitge1(&C[PRED_C], 65);
      float bv = -3.0e38f; int bi = 0;
      for (int v=tid; v<NVOCAB; v+=NT){
        float x = gld(&OUT[v]);
        if (x > bv){ bv = x; bi = v; }
      }
      L.f.xn[tid] = bv;
      ((int*)&L.f.xn[256])[tid] = bi;
      __syncthreads();
      for (int step=128; step; step>>=1){
        if (tid < step){
          float ov2 = L.f.xn[tid+step]; int oi = ((int*)&L.f.xn[256])[tid+step];
          float mv  = L.f.xn[tid];      int mi = ((int*)&L.f.xn[256])[tid];
          if (ov2 > mv || (ov2 == mv && oi < mi)){ L.f.xn[tid]=ov2; ((int*)&L.f.xn[256])[tid]=oi; }
        }
        __syncthreads();
      }
      if (tid == 0){
        int bi0 = ((int*)&L.f.xn[256])[0];
        OUT[NVOCAB]   = (float)bi0;
        OUT[NVOCAB+1] = (bi0 == 1024) ? 1.f : 0.f;
        OUT[NVOCAB+2] = (float)nlen;
        OUT[NVOCAB+3] = (float)(posi + 1);
      }
    }
  }
}

extern "C" void kernel_launch(void* const* d_in, const int* in_sizes, int n_in,
                              void* d_out, int out_size, void* d_ws, size_t ws_size,
                              hipStream_t stream) {
  (void)in_sizes; (void)n_in; (void)out_size; (void)ws_size;
  // zero counters/S (4096 B) + wop (65536 B) + wf2 (32768 B)
  hipMemsetAsync(d_ws, 0, 4096 + 65536 + 32768, stream);
  t2s_decode<<<GRID, NT, 0, stream>>>(
    (const int*)d_in[0], (const int*)d_in[1], (const int*)d_in[2],
    (const float*)d_in[3], (const float*)d_in[4],
    (const float*)d_in[5], (const float*)d_in[6],
    (const float*)d_in[7], (const float*)d_in[8],
    (const float*)d_in[9], (const float*)d_in[10],
    (const float*)d_in[11], (const float*)d_in[12],
    (const float*)d_in[13], (const float*)d_in[14],
    (const float*)d_in[15], (const float*)d_in[16],
    (const float*)d_in[17], (const float*)d_in[18],
    (const float*)d_in[19], (const float*)d_in[20],
    (const float*)d_in[21], (const float*)d_in[22],
    (float*)d_out, (float*)d_ws);
}